// Round 1
// 7170.630 us; speedup vs baseline: 1.7815x; 1.7815x over previous
//
#include <hip/hip_runtime.h>

#define SEQn   1024
#define BATCHn 64
#define EMBn   256
#define HIDn   512
#define VOCn   512

#define NL1 64
#define NL2 64
#define NFC 16
#define NBLK (NL1 + NL2 + NFC)   /* 144 blocks, <= 256 CUs -> all co-resident */
#define NPHASE (SEQn + 2)        /* 1026 phases: skewed L1 / L2 / FC pipeline */
#define HBUF (BATCHn * HIDn)     /* 32768 f16 = 64KB */

using f16   = _Float16;
using half8 = __attribute__((ext_vector_type(8))) _Float16;
using f32x4 = __attribute__((ext_vector_type(4))) float;

/* workspace layout (bytes) */
#define WS_CNT 0                            /* 16 phase slots x 128B     */
#define WS_H1  4096                         /* 4 rep x 2 par x 64KB      */
#define WS_H2  (WS_H1 + 8 * HBUF * 2)
#define WS_P1  (WS_H2 + 8 * HBUF * 2)       /* [512][2048] f16, 2MB      */

/* ---- tiled h layout ----
   h[mblk(4)][ks(16)][qq(4)][cc(16)][8 f16]  (64KB total)
   element (row r, col c) -> f16 index
     (((r>>4)*16 + (c>>5))*4 + ((c>>3)&3))*128 + (r&15)*8 + (c&7)
   A-fragment load for wave row-block W, lane l=qq*16+cc, slice ks:
     base = W*8192 + l*8, stride ks*512   -> lane-contiguous dwordx4.   */

__device__ __forceinline__ float sigm_(float v) { return 1.0f / (1.0f + __expf(-v)); }
__device__ __forceinline__ float tanh_(float v) { return 1.0f - 2.0f / (__expf(2.0f * v) + 1.0f); }

__device__ __forceinline__ void st_u32_sc1(f16* p, unsigned v) {
  asm volatile("global_store_dword %0, %1, off sc1" :: "v"(p), "v"(v) : "memory");
}
__device__ __forceinline__ void st_b128_sc1(f16* p, f32x4 v) {
  asm volatile("global_store_dwordx4 %0, %1, off sc1" :: "v"(p), "v"(v) : "memory");
}
__device__ __forceinline__ unsigned pack2(float a, float b) {
  f16 lo = (f16)a, hi = (f16)b;
  return (unsigned)__builtin_bit_cast(unsigned short, lo)
       | ((unsigned)__builtin_bit_cast(unsigned short, hi) << 16);
}

/* 16 x dwordx4 device-scope (sc1) loads + drain in ONE asm block: the
   s_waitcnt lives inside the asm, so no compiler-placed copy or hoisted
   MFMA can read an in-flight VMEM destination. Covers one 16KB M-block. */
__device__ __forceinline__ void ld_frag16(const f16* base, half8 (&a)[16]) {
  const f16* b0 = base + 2048;   /* +4KB  : ks 0..7 via signed offsets  */
  const f16* b1 = base + 6144;   /* +12KB : ks 8..15                    */
  f32x4 t0,t1,t2,t3,t4,t5,t6,t7,t8,t9,t10,t11,t12,t13,t14,t15;
  asm volatile(
    "global_load_dwordx4 %0,  %16, off offset:-4096 sc1\n\t"
    "global_load_dwordx4 %1,  %16, off offset:-3072 sc1\n\t"
    "global_load_dwordx4 %2,  %16, off offset:-2048 sc1\n\t"
    "global_load_dwordx4 %3,  %16, off offset:-1024 sc1\n\t"
    "global_load_dwordx4 %4,  %16, off sc1\n\t"
    "global_load_dwordx4 %5,  %16, off offset:1024 sc1\n\t"
    "global_load_dwordx4 %6,  %16, off offset:2048 sc1\n\t"
    "global_load_dwordx4 %7,  %16, off offset:3072 sc1\n\t"
    "global_load_dwordx4 %8,  %17, off offset:-4096 sc1\n\t"
    "global_load_dwordx4 %9,  %17, off offset:-3072 sc1\n\t"
    "global_load_dwordx4 %10, %17, off offset:-2048 sc1\n\t"
    "global_load_dwordx4 %11, %17, off offset:-1024 sc1\n\t"
    "global_load_dwordx4 %12, %17, off sc1\n\t"
    "global_load_dwordx4 %13, %17, off offset:1024 sc1\n\t"
    "global_load_dwordx4 %14, %17, off offset:2048 sc1\n\t"
    "global_load_dwordx4 %15, %17, off offset:3072 sc1\n\t"
    "s_waitcnt vmcnt(0)"
    : "=&v"(t0),"=&v"(t1),"=&v"(t2),"=&v"(t3),
      "=&v"(t4),"=&v"(t5),"=&v"(t6),"=&v"(t7),
      "=&v"(t8),"=&v"(t9),"=&v"(t10),"=&v"(t11),
      "=&v"(t12),"=&v"(t13),"=&v"(t14),"=&v"(t15)
    : "v"(b0), "v"(b1)
    : "memory");
  a[0]  = __builtin_bit_cast(half8, t0);   a[1]  = __builtin_bit_cast(half8, t1);
  a[2]  = __builtin_bit_cast(half8, t2);   a[3]  = __builtin_bit_cast(half8, t3);
  a[4]  = __builtin_bit_cast(half8, t4);   a[5]  = __builtin_bit_cast(half8, t5);
  a[6]  = __builtin_bit_cast(half8, t6);   a[7]  = __builtin_bit_cast(half8, t7);
  a[8]  = __builtin_bit_cast(half8, t8);   a[9]  = __builtin_bit_cast(half8, t9);
  a[10] = __builtin_bit_cast(half8, t10);  a[11] = __builtin_bit_cast(half8, t11);
  a[12] = __builtin_bit_cast(half8, t12);  a[13] = __builtin_bit_cast(half8, t13);
  a[14] = __builtin_bit_cast(half8, t14);  a[15] = __builtin_bit_cast(half8, t15);
}

/* ---- init: zero counters, seed all h1/h2 replicas (tiled layout) ---- */
__global__ void k_init(const float* __restrict__ h0, char* __restrict__ ws) {
  int i = blockIdx.x * 256 + threadIdx.x;          /* grid 1024*256 = 262144 */
  f16* h1b = (f16*)(ws + WS_H1);
  f16* h2b = (f16*)(ws + WS_H2);
  int e = i & (HBUF - 1);
  int r = e >> 9, c = e & 511;
  float v = h0[e];
  int t = (((r >> 4) * 16 + (c >> 5)) * 4 + ((c >> 3) & 3)) * 128 + (r & 15) * 8 + (c & 7);
  int b = i & ~(HBUF - 1);
  h1b[b + t] = (f16)v;
  h2b[b + t] = (f16)v;
  if (i < 1024) ((int*)ws)[i] = 0;
}

/* ---- P1[v][g] = emb[v] . Wih1[g] + bih1[g] + bhh1[g]  (fp16) ---- */
__global__ void k_p1(const float* __restrict__ emb, const float* __restrict__ Wih1,
                     const float* __restrict__ bih1, const float* __restrict__ bhh1,
                     char* __restrict__ ws) {
  __shared__ float elds[32 * 256];
  int tid = threadIdx.x;
  int vb = blockIdx.x >> 5, gb = blockIdx.x & 31;  /* grid 512 */
  for (int i = tid; i < 32 * 256; i += 256) elds[i] = emb[vb * 32 * 256 + i];
  __syncthreads();
  int gl = tid & 63, vs = tid >> 6;
  int g = gb * 64 + gl;
  float bias = bih1[g] + bhh1[g];
  float acc[8];
#pragma unroll
  for (int r = 0; r < 8; ++r) acc[r] = bias;
  const float* wrow = Wih1 + g * EMBn;
#pragma unroll 4
  for (int e = 0; e < EMBn; ++e) {
    float w = wrow[e];
#pragma unroll
    for (int r = 0; r < 8; ++r) acc[r] += elds[(vs * 8 + r) * 256 + e] * w;
  }
  f16* P1 = (f16*)(ws + WS_P1);
#pragma unroll
  for (int r = 0; r < 8; ++r) P1[(vb * 32 + vs * 8 + r) * 2048 + g] = (f16)acc[r];
}

/* ---- persistent skewed-pipeline kernel ---- */
__global__ void __launch_bounds__(256, 1)
k_lstm(const int* __restrict__ x, const float* __restrict__ c0,
       const float* __restrict__ Whh1,
       const float* __restrict__ Wih2, const float* __restrict__ Whh2,
       const float* __restrict__ bih2, const float* __restrict__ bhh2,
       const float* __restrict__ Wfc, const float* __restrict__ bfc,
       float* __restrict__ out, char* __restrict__ ws)
{
  __shared__ float part[2][64][33];    /* L2 partial gates: [K-half][row][col] */
  __shared__ f16 p1s[VOCn * 32];       /* L1 P1 slice [512 vocab][32 cols]     */

  f16* h1base = (f16*)(ws + WS_H1);
  f16* h2base = (f16*)(ws + WS_H2);
  const f16* P1 = (const f16*)(ws + WS_P1);

  const int bid = blockIdx.x, tid = threadIdx.x;
  const int lane = tid & 63, wv = tid >> 6;
  const int cc = lane & 15, qq = lane >> 4;
  const int rep = bid & 3;             /* which h replica this block reads */

  half8 bfrA[2][16];                   /* weight B-fragments, resident all run */
  float cst[4] = {0.f, 0.f, 0.f, 0.f};
  float bias0 = 0.f, bias1 = 0.f;
  int j0 = 0;
  /* L2 wave roles */
  const int khalf = wv >> 1;           /* 0: h1/Wih2, 1: h2/Whh2 */
  const int mh = wv & 1;               /* M 32-row half */

  if (bid < NL1) {
    /* layer-1: 8 units; cols = [i x8][f x8] tile0, [g x8][o x8] tile1 */
    j0 = bid * 8;
    int g0 = (cc >> 3) * 512 + j0 + (cc & 7);
#pragma unroll
    for (int nt = 0; nt < 2; ++nt) {
      const float* wr = Whh1 + (g0 + nt * 1024) * HIDn;
#pragma unroll
      for (int ks = 0; ks < 16; ++ks) {
        const float* s = wr + ks * 32 + qq * 8;
        half8 hv;
#pragma unroll
        for (int j = 0; j < 8; ++j) hv[j] = (f16)s[j];
        bfrA[nt][ks] = hv;
      }
    }
    for (int i = tid; i < VOCn * 32; i += 256) {
      int v = i >> 5, n = i & 31;
      p1s[i] = P1[v * 2048 + (n >> 3) * 512 + j0 + (n & 7)];
    }
    if (cc < 8) {
#pragma unroll
      for (int r = 0; r < 4; ++r)
        cst[r] = c0[(wv * 16 + qq * 4 + r) * HIDn + j0 + cc];
    }
  } else if (bid < NL1 + NL2) {
    /* layer-2: 8 units; waves split (K-half x M-half); cols as L1 */
    j0 = (bid - NL1) * 8;
    int g0 = (cc >> 3) * 512 + j0 + (cc & 7);
    const float* W = khalf ? Whh2 : Wih2;
#pragma unroll
    for (int nt = 0; nt < 2; ++nt) {
      const float* wr = W + (g0 + nt * 1024) * HIDn;
#pragma unroll
      for (int ks = 0; ks < 16; ++ks) {
        const float* s = wr + ks * 32 + qq * 8;
        half8 hv;
#pragma unroll
        for (int j = 0; j < 8; ++j) hv[j] = (f16)s[j];
        bfrA[nt][ks] = hv;
      }
    }
    if (khalf == 0) {
      int gc0 = g0, gc1 = g0 + 1024;
      bias0 = bih2[gc0] + bhh2[gc0];
      bias1 = bih2[gc1] + bhh2[gc1];
    }
    /* epilogue cell state: thread owns (m = tid>>2, units 2u, 2u+1) */
    {
      int m = tid >> 2, u = tid & 3;
      cst[0] = c0[m * HIDn + j0 + 2 * u];
      cst[1] = c0[m * HIDn + j0 + 2 * u + 1];
    }
  } else {
    /* FC: 32 vocab cols */
    j0 = (bid - NL1 - NL2) * 32;
#pragma unroll
    for (int nt = 0; nt < 2; ++nt) {
      const float* wr = Wfc + (j0 + nt * 16 + cc) * HIDn;
#pragma unroll
      for (int ks = 0; ks < 16; ++ks) {
        const float* s = wr + ks * 32 + qq * 8;
        half8 hv;
#pragma unroll
        for (int j = 0; j < 8; ++j) hv[j] = (f16)s[j];
        bfrA[nt][ks] = hv;
      }
    }
    bias0 = bfc[j0 + cc];
    bias1 = bfc[j0 + 16 + cc];
  }
  /* per-block unit window inside the tiled ks/qq grid (L1/L2) */
  const int ksJ = (j0 >> 5), qqJ = (j0 >> 3) & 3;
  __syncthreads();

  for (int p = 1; p <= NPHASE; ++p) {
    if (bid < NL1) {
      if (p <= SEQn) {                 /* h1_p = f(h1_{p-1}, x_{p-1}) */
        const f16* hp = h1base + (rep * 2 + ((p - 1) & 1)) * HBUF;
        /* overlap LDS/x gathers with nothing-in-flight, then drain loads */
        f32x4 acc0, acc1;
#pragma unroll
        for (int r = 0; r < 4; ++r) {
          int xv = x[(p - 1) * 64 + wv * 16 + qq * 4 + r];
          acc0[r] = (float)p1s[xv * 32 + cc];
          acc1[r] = (float)p1s[xv * 32 + 16 + cc];
        }
        half8 a[16];
        ld_frag16(hp + wv * 8192 + lane * 8, a);
#pragma unroll
        for (int ks = 0; ks < 16; ++ks) {
          acc0 = __builtin_amdgcn_mfma_f32_16x16x32_f16(a[ks], bfrA[0][ks], acc0, 0, 0, 0);
          acc1 = __builtin_amdgcn_mfma_f32_16x16x32_f16(a[ks], bfrA[1][ks], acc1, 0, 0, 0);
        }
        float hv4[4];
#pragma unroll
        for (int r = 0; r < 4; ++r) {
          float fv = __shfl_xor(acc0[r], 8);
          float ov = __shfl_xor(acc1[r], 8);
          float iv = sigm_(acc0[r]);
          float gv = tanh_(acc1[r]);
          float ff = sigm_(fv);
          float oo = sigm_(ov);
          float cn = ff * cst[r] + iv * gv;
          cst[r] = cn;                 /* garbage for cc>=8, never consumed */
          hv4[r] = oo * tanh_(cn);
        }
        /* pack 8 units (lanes cc=0..7) into one 16B dwordx4 at cc==0 */
#pragma unroll
        for (int r = 0; r < 4; ++r) {
          unsigned p01 = pack2(hv4[r], __shfl_xor(hv4[r], 1));
          unsigned p23 = __shfl_xor(p01, 2);
          unsigned p45 = __shfl_xor(p01, 4);
          unsigned p67 = __shfl_xor(p23, 4);
          if (cc == 0) {
            f32x4 w;
            w[0] = __builtin_bit_cast(float, p01);
            w[1] = __builtin_bit_cast(float, p23);
            w[2] = __builtin_bit_cast(float, p45);
            w[3] = __builtin_bit_cast(float, p67);
            int off = wv * 8192 + ksJ * 512 + qqJ * 128 + (qq * 4 + r) * 8;
#pragma unroll
            for (int rp = 0; rp < 4; ++rp)
              st_b128_sc1(h1base + (rp * 2 + (p & 1)) * HBUF + off, w);
          }
        }
      }
    } else if (bid < NL1 + NL2) {
      if (p >= 2 && p <= SEQn + 1) {   /* h2_{p-1} = f(h1_{p-1}, h2_{p-2}) */
        const f16* src = (khalf == 0)
            ? h1base + (rep * 2 + ((p - 1) & 1)) * HBUF
            : h2base + (rep * 2 + (p & 1)) * HBUF;
        f32x4 acc[2][2];
#pragma unroll
        for (int mt = 0; mt < 2; ++mt)
#pragma unroll
          for (int r = 0; r < 4; ++r) {
            acc[mt][0][r] = (khalf == 0) ? bias0 : 0.f;
            acc[mt][1][r] = (khalf == 0) ? bias1 : 0.f;
          }
#pragma unroll
        for (int mt = 0; mt < 2; ++mt) {
          half8 a[16];
          ld_frag16(src + (mh * 2 + mt) * 8192 + lane * 8, a);
#pragma unroll
          for (int ks = 0; ks < 16; ++ks) {
            acc[mt][0] = __builtin_amdgcn_mfma_f32_16x16x32_f16(a[ks], bfrA[0][ks], acc[mt][0], 0, 0, 0);
            acc[mt][1] = __builtin_amdgcn_mfma_f32_16x16x32_f16(a[ks], bfrA[1][ks], acc[mt][1], 0, 0, 0);
          }
        }
#pragma unroll
        for (int mt = 0; mt < 2; ++mt)
#pragma unroll
          for (int nt = 0; nt < 2; ++nt)
#pragma unroll
            for (int r = 0; r < 4; ++r)
              part[khalf][mh * 32 + mt * 16 + qq * 4 + r][nt * 16 + cc] = acc[mt][nt][r];
        __syncthreads();
        {
          int m = tid >> 2, u = tid & 3;
          f16* ho = h2base + ((p - 1) & 1) * HBUF;  /* + rep offset below */
          float hh[2];
#pragma unroll
          for (int w2 = 0; w2 < 2; ++w2) {
            int w = 2 * u + w2;
            float gi = part[0][m][w]      + part[1][m][w];
            float gf = part[0][m][8 + w]  + part[1][m][8 + w];
            float gg = part[0][m][16 + w] + part[1][m][16 + w];
            float go = part[0][m][24 + w] + part[1][m][24 + w];
            float cn = sigm_(gf) * cst[w2] + sigm_(gi) * tanh_(gg);
            cst[w2] = cn;
            hh[w2] = sigm_(go) * tanh_(cn);
          }
          unsigned u32v = pack2(hh[0], hh[1]);
          /* tiled: per-wave contiguous 256B run (lane*4 bytes) */
          int off = wv * 8192 + ksJ * 512 + qqJ * 128 + lane * 2;
#pragma unroll
          for (int rp = 0; rp < 4; ++rp)
            st_u32_sc1(ho + rp * 2 * HBUF + off, u32v);
        }
      }
    } else {
      if (p >= 3) {                    /* out_{p-3} = h2_{p-2} @ WfcT + bfc */
        const f16* h2p = h2base + (rep * 2 + (p & 1)) * HBUF;
        float* op = out + (size_t)(p - 3) * (BATCHn * VOCn);
        half8 a[16];
        ld_frag16(h2p + wv * 8192 + lane * 8, a);
        f32x4 acc0, acc1;
#pragma unroll
        for (int r = 0; r < 4; ++r) { acc0[r] = bias0; acc1[r] = bias1; }
#pragma unroll
        for (int ks = 0; ks < 16; ++ks) {
          acc0 = __builtin_amdgcn_mfma_f32_16x16x32_f16(a[ks], bfrA[0][ks], acc0, 0, 0, 0);
          acc1 = __builtin_amdgcn_mfma_f32_16x16x32_f16(a[ks], bfrA[1][ks], acc1, 0, 0, 0);
        }
#pragma unroll
        for (int r = 0; r < 4; ++r) {
          int m = wv * 16 + qq * 4 + r;
          __builtin_nontemporal_store(acc0[r], &op[m * VOCn + j0 + cc]);
          __builtin_nontemporal_store(acc1[r], &op[m * VOCn + j0 + 16 + cc]);
        }
      }
    }

    /* ---- phase barrier: counter arrivals + single-line lazy poll ----
       producers drain sc1 h-stores to the MALL first (store-at-coherence-
       point replaces a release fence); FC skips the drain (out stores are
       fire-and-forget). Only tid 0 polls: one line, ~2 reqs/us per block. */
    if (bid < NL1 + NL2) asm volatile("s_waitcnt vmcnt(0)" ::: "memory");
    __syncthreads();
    if (tid == 0) {
      unsigned* cnt = (unsigned*)(ws + ((p & 15) * 128));
      __hip_atomic_fetch_add(cnt, 1u, __ATOMIC_RELAXED, __HIP_MEMORY_SCOPE_AGENT);
      while (__hip_atomic_load(cnt, __ATOMIC_RELAXED, __HIP_MEMORY_SCOPE_AGENT) < NBLK)
        __builtin_amdgcn_s_sleep(8);
      if (bid == 0)
        __hip_atomic_store((unsigned*)(ws + (((p + 8) & 15) * 128)), 0u,
                           __ATOMIC_RELAXED, __HIP_MEMORY_SCOPE_AGENT);
    }
    __syncthreads();
  }
}

extern "C" void kernel_launch(void* const* d_in, const int* in_sizes, int n_in,
                              void* d_out, int out_size, void* d_ws, size_t ws_size,
                              hipStream_t stream) {
  (void)in_sizes; (void)n_in; (void)out_size; (void)ws_size;
  const int*   x    = (const int*)  d_in[0];
  const float* h0   = (const float*)d_in[1];
  const float* c0   = (const float*)d_in[2];
  const float* emb  = (const float*)d_in[3];
  const float* Wih1 = (const float*)d_in[4];
  const float* Whh1 = (const float*)d_in[5];
  const float* bih1 = (const float*)d_in[6];
  const float* bhh1 = (const float*)d_in[7];
  const float* Wih2 = (const float*)d_in[8];
  const float* Whh2 = (const float*)d_in[9];
  const float* bih2 = (const float*)d_in[10];
  const float* bhh2 = (const float*)d_in[11];
  const float* Wfc  = (const float*)d_in[12];
  const float* bfc  = (const float*)d_in[13];
  char* ws = (char*)d_ws;

  hipLaunchKernelGGL(k_init, dim3(1024), dim3(256), 0, stream, h0, ws);
  hipLaunchKernelGGL(k_p1,   dim3(512), dim3(256), 0, stream, emb, Wih1, bih1, bhh1, ws);
  hipLaunchKernelGGL(k_lstm, dim3(NBLK), dim3(256), 0, stream,
                     x, c0, Whh1, Wih2, Whh2, bih2, bhh2, Wfc, bfc,
                     (float*)d_out, ws);
}

// Round 2
// 5753.861 us; speedup vs baseline: 2.2202x; 1.2462x over previous
//
#include <hip/hip_runtime.h>

#define SEQn   1024
#define BATCHn 64
#define EMBn   256
#define HIDn   512
#define VOCn   512

#define NL1 64
#define NL2 64
#define NFC 16
#define NBLK (NL1 + NL2 + NFC)   /* 144 blocks, <= 256 CUs -> all co-resident */
#define NPHASE (SEQn + 2)        /* 1026 phases: skewed L1 / L2 / FC pipeline */
#define HBUF (BATCHn * HIDn)     /* 32768 f16 = 64KB */

using f16   = _Float16;
using half8 = __attribute__((ext_vector_type(8))) _Float16;
using f32x4 = __attribute__((ext_vector_type(4))) float;
using i32x4 = __attribute__((ext_vector_type(4))) int;

/* workspace layout (bytes) */
#define WS_FLG 0                            /* 144 monotonic phase flags  */
#define WS_H1  4096                         /* 4 rep x 2 par x 64KB       */
#define WS_H2  (WS_H1 + 8 * HBUF * 2)
#define WS_P1  (WS_H2 + 8 * HBUF * 2)       /* [512][2048] f16, 2MB       */

/* ---- tiled h layout ----
   h[mblk(4)][ks(16)][qq(4)][cc(16)][8 f16]  (64KB total)
   element (row r, col c) -> f16 index
     (((r>>4)*16 + (c>>5))*4 + ((c>>3)&3))*128 + (r&15)*8 + (c&7)
   A-fragment load for wave row-block W, lane l=qq*16+cc, slice ks:
     base = W*8192 + l*8, stride ks*512   -> lane-contiguous dwordx4.   */

__device__ __forceinline__ float sigm_(float v) { return 1.0f / (1.0f + __expf(-v)); }
__device__ __forceinline__ float tanh_(float v) { return 1.0f - 2.0f / (__expf(2.0f * v) + 1.0f); }

__device__ __forceinline__ void st_u32_sc1(f16* p, unsigned v) {
  asm volatile("global_store_dword %0, %1, off sc1" :: "v"(p), "v"(v) : "memory");
}
__device__ __forceinline__ void st_b128_sc1(f16* p, f32x4 v) {
  asm volatile("global_store_dwordx4 %0, %1, off sc1" :: "v"(p), "v"(v) : "memory");
}
__device__ __forceinline__ unsigned pack2(float a, float b) {
  f16 lo = (f16)a, hi = (f16)b;
  return (unsigned)__builtin_bit_cast(unsigned short, lo)
       | ((unsigned)__builtin_bit_cast(unsigned short, hi) << 16);
}

/* 16 x dwordx4 device-scope (sc1) loads + drain in ONE asm block: the
   s_waitcnt lives inside the asm, so no compiler-placed copy or hoisted
   MFMA can read an in-flight VMEM destination. Covers one 16KB M-block. */
__device__ __forceinline__ void ld_frag16(const f16* base, half8 (&a)[16]) {
  const f16* b0 = base + 2048;   /* +4KB  : ks 0..7 via signed offsets  */
  const f16* b1 = base + 6144;   /* +12KB : ks 8..15                    */
  f32x4 t0,t1,t2,t3,t4,t5,t6,t7,t8,t9,t10,t11,t12,t13,t14,t15;
  asm volatile(
    "global_load_dwordx4 %0,  %16, off offset:-4096 sc1\n\t"
    "global_load_dwordx4 %1,  %16, off offset:-3072 sc1\n\t"
    "global_load_dwordx4 %2,  %16, off offset:-2048 sc1\n\t"
    "global_load_dwordx4 %3,  %16, off offset:-1024 sc1\n\t"
    "global_load_dwordx4 %4,  %16, off sc1\n\t"
    "global_load_dwordx4 %5,  %16, off offset:1024 sc1\n\t"
    "global_load_dwordx4 %6,  %16, off offset:2048 sc1\n\t"
    "global_load_dwordx4 %7,  %16, off offset:3072 sc1\n\t"
    "global_load_dwordx4 %8,  %17, off offset:-4096 sc1\n\t"
    "global_load_dwordx4 %9,  %17, off offset:-3072 sc1\n\t"
    "global_load_dwordx4 %10, %17, off offset:-2048 sc1\n\t"
    "global_load_dwordx4 %11, %17, off offset:-1024 sc1\n\t"
    "global_load_dwordx4 %12, %17, off sc1\n\t"
    "global_load_dwordx4 %13, %17, off offset:1024 sc1\n\t"
    "global_load_dwordx4 %14, %17, off offset:2048 sc1\n\t"
    "global_load_dwordx4 %15, %17, off offset:3072 sc1\n\t"
    "s_waitcnt vmcnt(0)"
    : "=&v"(t0),"=&v"(t1),"=&v"(t2),"=&v"(t3),
      "=&v"(t4),"=&v"(t5),"=&v"(t6),"=&v"(t7),
      "=&v"(t8),"=&v"(t9),"=&v"(t10),"=&v"(t11),
      "=&v"(t12),"=&v"(t13),"=&v"(t14),"=&v"(t15)
    : "v"(b0), "v"(b1)
    : "memory");
  a[0]  = __builtin_bit_cast(half8, t0);   a[1]  = __builtin_bit_cast(half8, t1);
  a[2]  = __builtin_bit_cast(half8, t2);   a[3]  = __builtin_bit_cast(half8, t3);
  a[4]  = __builtin_bit_cast(half8, t4);   a[5]  = __builtin_bit_cast(half8, t5);
  a[6]  = __builtin_bit_cast(half8, t6);   a[7]  = __builtin_bit_cast(half8, t7);
  a[8]  = __builtin_bit_cast(half8, t8);   a[9]  = __builtin_bit_cast(half8, t9);
  a[10] = __builtin_bit_cast(half8, t10);  a[11] = __builtin_bit_cast(half8, t11);
  a[12] = __builtin_bit_cast(half8, t12);  a[13] = __builtin_bit_cast(half8, t13);
  a[14] = __builtin_bit_cast(half8, t14);  a[15] = __builtin_bit_cast(half8, t15);
}

/* ---- init: zero flags, seed all h1/h2 replicas (tiled layout) ---- */
__global__ void k_init(const float* __restrict__ h0, char* __restrict__ ws) {
  int i = blockIdx.x * 256 + threadIdx.x;          /* grid 1024*256 = 262144 */
  f16* h1b = (f16*)(ws + WS_H1);
  f16* h2b = (f16*)(ws + WS_H2);
  int e = i & (HBUF - 1);
  int r = e >> 9, c = e & 511;
  float v = h0[e];
  int t = (((r >> 4) * 16 + (c >> 5)) * 4 + ((c >> 3) & 3)) * 128 + (r & 15) * 8 + (c & 7);
  int b = i & ~(HBUF - 1);
  h1b[b + t] = (f16)v;
  h2b[b + t] = (f16)v;
  if (i < 1024) ((int*)ws)[i] = 0;
}

/* ---- P1[v][g] = emb[v] . Wih1[g] + bih1[g] + bhh1[g]  (fp16) ---- */
__global__ void k_p1(const float* __restrict__ emb, const float* __restrict__ Wih1,
                     const float* __restrict__ bih1, const float* __restrict__ bhh1,
                     char* __restrict__ ws) {
  __shared__ float elds[32 * 256];
  int tid = threadIdx.x;
  int vb = blockIdx.x >> 5, gb = blockIdx.x & 31;  /* grid 512 */
  for (int i = tid; i < 32 * 256; i += 256) elds[i] = emb[vb * 32 * 256 + i];
  __syncthreads();
  int gl = tid & 63, vs = tid >> 6;
  int g = gb * 64 + gl;
  float bias = bih1[g] + bhh1[g];
  float acc[8];
#pragma unroll
  for (int r = 0; r < 8; ++r) acc[r] = bias;
  const float* wrow = Wih1 + g * EMBn;
#pragma unroll 4
  for (int e = 0; e < EMBn; ++e) {
    float w = wrow[e];
#pragma unroll
    for (int r = 0; r < 8; ++r) acc[r] += elds[(vs * 8 + r) * 256 + e] * w;
  }
  f16* P1 = (f16*)(ws + WS_P1);
#pragma unroll
  for (int r = 0; r < 8; ++r) P1[(vb * 32 + vs * 8 + r) * 2048 + g] = (f16)acc[r];
}

/* ---- persistent skewed-pipeline kernel ---- */
__global__ void __launch_bounds__(256, 1)
k_lstm(const int* __restrict__ x, const float* __restrict__ c0,
       const float* __restrict__ Whh1,
       const float* __restrict__ Wih2, const float* __restrict__ Whh2,
       const float* __restrict__ bih2, const float* __restrict__ bhh2,
       const float* __restrict__ Wfc, const float* __restrict__ bfc,
       float* __restrict__ out, char* __restrict__ ws)
{
  __shared__ float part[2][64][34];    /* L2 partial gates (stride 34: bank-pad) */
  __shared__ f16 p1s[VOCn * 32];       /* L1 P1 slice [512 vocab][32 cols]       */
  __shared__ alignas(16) f16 hstage[4][16][8];  /* L1 h-pack staging, 1KB        */

  f16* h1base = (f16*)(ws + WS_H1);
  f16* h2base = (f16*)(ws + WS_H2);
  const f16* P1 = (const f16*)(ws + WS_P1);

  const int bid = blockIdx.x, tid = threadIdx.x;
  const int lane = tid & 63, wv = tid >> 6;
  const int cc = lane & 15, qq = lane >> 4;
  const int rep = bid & 3;             /* which h replica this block reads */

  half8 bfrA[2][16];                   /* weight B-fragments, resident all run */
  float cst[4] = {0.f, 0.f, 0.f, 0.f};
  float bias0 = 0.f, bias1 = 0.f;
  int j0 = 0;
  /* L2 wave roles */
  const int khalf = wv >> 1;           /* 0: h1/Wih2, 1: h2/Whh2 */
  const int mh = wv & 1;               /* M 32-row half */

  if (bid < NL1) {
    /* layer-1: 8 units; cols = [i x8][f x8] tile0, [g x8][o x8] tile1 */
    j0 = bid * 8;
    int g0 = (cc >> 3) * 512 + j0 + (cc & 7);
#pragma unroll
    for (int nt = 0; nt < 2; ++nt) {
      const float* wr = Whh1 + (g0 + nt * 1024) * HIDn;
#pragma unroll
      for (int ks = 0; ks < 16; ++ks) {
        const float* s = wr + ks * 32 + qq * 8;
        half8 hv;
#pragma unroll
        for (int j = 0; j < 8; ++j) hv[j] = (f16)s[j];
        bfrA[nt][ks] = hv;
      }
    }
    for (int i = tid; i < VOCn * 32; i += 256) {
      int v = i >> 5, n = i & 31;
      p1s[i] = P1[v * 2048 + (n >> 3) * 512 + j0 + (n & 7)];
    }
    if (cc < 8) {
#pragma unroll
      for (int r = 0; r < 4; ++r)
        cst[r] = c0[(wv * 16 + qq * 4 + r) * HIDn + j0 + cc];
    }
  } else if (bid < NL1 + NL2) {
    /* layer-2: 8 units; waves split (K-half x M-half); cols as L1 */
    j0 = (bid - NL1) * 8;
    int g0 = (cc >> 3) * 512 + j0 + (cc & 7);
    const float* W = khalf ? Whh2 : Wih2;
#pragma unroll
    for (int nt = 0; nt < 2; ++nt) {
      const float* wr = W + (g0 + nt * 1024) * HIDn;
#pragma unroll
      for (int ks = 0; ks < 16; ++ks) {
        const float* s = wr + ks * 32 + qq * 8;
        half8 hv;
#pragma unroll
        for (int j = 0; j < 8; ++j) hv[j] = (f16)s[j];
        bfrA[nt][ks] = hv;
      }
    }
    if (khalf == 0) {
      int gc0 = g0, gc1 = g0 + 1024;
      bias0 = bih2[gc0] + bhh2[gc0];
      bias1 = bih2[gc1] + bhh2[gc1];
    }
    /* epilogue cell state: thread owns (m = tid>>2, units 2u, 2u+1) */
    {
      int m = tid >> 2, u = tid & 3;
      cst[0] = c0[m * HIDn + j0 + 2 * u];
      cst[1] = c0[m * HIDn + j0 + 2 * u + 1];
    }
  } else {
    /* FC: 32 vocab cols */
    j0 = (bid - NL1 - NL2) * 32;
#pragma unroll
    for (int nt = 0; nt < 2; ++nt) {
      const float* wr = Wfc + (j0 + nt * 16 + cc) * HIDn;
#pragma unroll
      for (int ks = 0; ks < 16; ++ks) {
        const float* s = wr + ks * 32 + qq * 8;
        half8 hv;
#pragma unroll
        for (int j = 0; j < 8; ++j) hv[j] = (f16)s[j];
        bfrA[nt][ks] = hv;
      }
    }
    bias0 = bfc[j0 + cc];
    bias1 = bfc[j0 + 16 + cc];
  }
  /* per-block unit window inside the tiled ks/qq grid (L1/L2) */
  const int ksJ = (j0 >> 5), qqJ = (j0 >> 3) & 3;
  __syncthreads();

  /* L1: pre-gather the x/P1 accumulator for phase 1 (overlaps nothing yet) */
  f32x4 pg0, pg1;
  if (bid < NL1) {
#pragma unroll
    for (int r = 0; r < 4; ++r) {
      int xv = x[wv * 16 + qq * 4 + r];
      pg0[r] = (float)p1s[xv * 32 + cc];
      pg1[r] = (float)p1s[xv * 32 + 16 + cc];
    }
  }

  for (int p = 1; p <= NPHASE; ++p) {
    if (bid < NL1) {
      if (p <= SEQn) {                 /* h1_p = f(h1_{p-1}, x_{p-1}) */
        const f16* hp = h1base + (rep * 2 + ((p - 1) & 1)) * HBUF;
        f32x4 acc0 = pg0, acc1 = pg1;  /* pre-gathered during prior barrier */
        half8 a[16];
        ld_frag16(hp + wv * 8192 + lane * 8, a);
#pragma unroll
        for (int ks = 0; ks < 16; ++ks) {
          acc0 = __builtin_amdgcn_mfma_f32_16x16x32_f16(a[ks], bfrA[0][ks], acc0, 0, 0, 0);
          acc1 = __builtin_amdgcn_mfma_f32_16x16x32_f16(a[ks], bfrA[1][ks], acc1, 0, 0, 0);
        }
        float hv4[4];
#pragma unroll
        for (int r = 0; r < 4; ++r) {
          float fv = __shfl_xor(acc0[r], 8);
          float ov = __shfl_xor(acc1[r], 8);
          float iv = sigm_(acc0[r]);
          float gv = tanh_(acc1[r]);
          float ff = sigm_(fv);
          float oo = sigm_(ov);
          float cn = ff * cst[r] + iv * gv;
          cst[r] = cn;                 /* garbage for cc>=8, never consumed */
          hv4[r] = oo * tanh_(cn);
        }
        /* stage h through LDS -> 4 dense wave-wide dwordx4 stores (1 per rep) */
        if (cc < 8) {
#pragma unroll
          for (int r = 0; r < 4; ++r)
            hstage[wv][qq * 4 + r][cc] = (f16)hv4[r];
        }
        __syncthreads();
        {
          f32x4 w = *(const f32x4*)&hstage[lane >> 4][lane & 15][0];
          f16* dst = h1base + (wv * 2 + (p & 1)) * HBUF
                   + (lane >> 4) * 8192 + ksJ * 512 + qqJ * 128 + (lane & 15) * 8;
          st_b128_sc1(dst, w);
        }
      }
    } else if (bid < NL1 + NL2) {
      if (p >= 2 && p <= SEQn + 1) {   /* h2_{p-1} = f(h1_{p-1}, h2_{p-2}) */
        const f16* src = (khalf == 0)
            ? h1base + (rep * 2 + ((p - 1) & 1)) * HBUF
            : h2base + (rep * 2 + (p & 1)) * HBUF;
        f32x4 acc[2][2];
#pragma unroll
        for (int mt = 0; mt < 2; ++mt)
#pragma unroll
          for (int r = 0; r < 4; ++r) {
            acc[mt][0][r] = (khalf == 0) ? bias0 : 0.f;
            acc[mt][1][r] = (khalf == 0) ? bias1 : 0.f;
          }
#pragma unroll
        for (int mt = 0; mt < 2; ++mt) {
          half8 a[16];
          ld_frag16(src + (mh * 2 + mt) * 8192 + lane * 8, a);
#pragma unroll
          for (int ks = 0; ks < 16; ++ks) {
            acc[mt][0] = __builtin_amdgcn_mfma_f32_16x16x32_f16(a[ks], bfrA[0][ks], acc[mt][0], 0, 0, 0);
            acc[mt][1] = __builtin_amdgcn_mfma_f32_16x16x32_f16(a[ks], bfrA[1][ks], acc[mt][1], 0, 0, 0);
          }
        }
#pragma unroll
        for (int mt = 0; mt < 2; ++mt)
#pragma unroll
          for (int nt = 0; nt < 2; ++nt)
#pragma unroll
            for (int r = 0; r < 4; ++r)
              part[khalf][mh * 32 + mt * 16 + qq * 4 + r][nt * 16 + cc] = acc[mt][nt][r];
        __syncthreads();
        {
          int m = tid >> 2, u = tid & 3;
          f16* ho = h2base + ((p - 1) & 1) * HBUF;  /* + rep offset below */
          float hh[2];
#pragma unroll
          for (int w2 = 0; w2 < 2; ++w2) {
            int w = 2 * u + w2;
            float gi = part[0][m][w]      + part[1][m][w];
            float gf = part[0][m][8 + w]  + part[1][m][8 + w];
            float gg = part[0][m][16 + w] + part[1][m][16 + w];
            float go = part[0][m][24 + w] + part[1][m][24 + w];
            float cn = sigm_(gf) * cst[w2] + sigm_(gi) * tanh_(gg);
            cst[w2] = cn;
            hh[w2] = sigm_(go) * tanh_(cn);
          }
          unsigned u32v = pack2(hh[0], hh[1]);
          /* tiled: per-wave contiguous 256B run (lane*4 bytes) */
          int off = wv * 8192 + ksJ * 512 + qqJ * 128 + lane * 2;
#pragma unroll
          for (int rp = 0; rp < 4; ++rp)
            st_u32_sc1(ho + rp * 2 * HBUF + off, u32v);
        }
      }
    } else {
      if (p >= 3) {                    /* out_{p-3} = h2_{p-2} @ WfcT + bfc */
        const f16* h2p = h2base + (rep * 2 + (p & 1)) * HBUF;
        float* op = out + (size_t)(p - 3) * (BATCHn * VOCn);
        half8 a[16];
        ld_frag16(h2p + wv * 8192 + lane * 8, a);
        f32x4 acc0, acc1;
#pragma unroll
        for (int r = 0; r < 4; ++r) { acc0[r] = bias0; acc1[r] = bias1; }
#pragma unroll
        for (int ks = 0; ks < 16; ++ks) {
          acc0 = __builtin_amdgcn_mfma_f32_16x16x32_f16(a[ks], bfrA[0][ks], acc0, 0, 0, 0);
          acc1 = __builtin_amdgcn_mfma_f32_16x16x32_f16(a[ks], bfrA[1][ks], acc1, 0, 0, 0);
        }
#pragma unroll
        for (int r = 0; r < 4; ++r) {
          int m = wv * 16 + qq * 4 + r;
          __builtin_nontemporal_store(acc0[r], &op[m * VOCn + j0 + cc]);
          __builtin_nontemporal_store(acc1[r], &op[m * VOCn + j0 + 16 + cc]);
        }
      }
    }

    /* ---- phase barrier: per-block monotonic flag + wave-parallel poll ----
       arrival: ONE sc1 dword store to own slot (no atomic RMW contention);
       detection: wave 0, lanes 0..35 load 4 flags each (dwordx4 sc1) and
       __all(flags >= p). Producers drain sc1 h-stores first so flag
       publication orders after data at the MALL coherence point. */
    if (bid < NL1 + NL2) asm volatile("s_waitcnt vmcnt(0)" ::: "memory");
    __syncthreads();
    if (tid == 0)
      asm volatile("global_store_dword %0, %1, off sc1"
                   :: "v"((int*)ws + bid), "v"(p) : "memory");
    /* L1: pre-gather next phase's x/P1 accumulator under the barrier wait */
    if (bid < NL1 && p < SEQn) {
#pragma unroll
      for (int r = 0; r < 4; ++r) {
        int xv = x[p * 64 + wv * 16 + qq * 4 + r];
        pg0[r] = (float)p1s[xv * 32 + cc];
        pg1[r] = (float)p1s[xv * 32 + 16 + cc];
      }
    }
    if (wv == 0) {
      const int* fp = (const int*)ws + (lane << 2);
      for (;;) {
        i32x4 f;
        asm volatile("global_load_dwordx4 %0, %1, off sc1\n\ts_waitcnt vmcnt(0)"
                     : "=v"(f) : "v"(fp) : "memory");
        int ok = (lane >= 36) ||
                 ((f[0] >= p) & (f[1] >= p) & (f[2] >= p) & (f[3] >= p));
        if (__all(ok)) break;
        __builtin_amdgcn_s_sleep(2);
      }
    }
    __syncthreads();
  }
}

extern "C" void kernel_launch(void* const* d_in, const int* in_sizes, int n_in,
                              void* d_out, int out_size, void* d_ws, size_t ws_size,
                              hipStream_t stream) {
  (void)in_sizes; (void)n_in; (void)out_size; (void)ws_size;
  const int*   x    = (const int*)  d_in[0];
  const float* h0   = (const float*)d_in[1];
  const float* c0   = (const float*)d_in[2];
  const float* emb  = (const float*)d_in[3];
  const float* Wih1 = (const float*)d_in[4];
  const float* Whh1 = (const float*)d_in[5];
  const float* bih1 = (const float*)d_in[6];
  const float* bhh1 = (const float*)d_in[7];
  const float* Wih2 = (const float*)d_in[8];
  const float* Whh2 = (const float*)d_in[9];
  const float* bih2 = (const float*)d_in[10];
  const float* bhh2 = (const float*)d_in[11];
  const float* Wfc  = (const float*)d_in[12];
  const float* bfc  = (const float*)d_in[13];
  char* ws = (char*)d_ws;

  hipLaunchKernelGGL(k_init, dim3(1024), dim3(256), 0, stream, h0, ws);
  hipLaunchKernelGGL(k_p1,   dim3(512), dim3(256), 0, stream, emb, Wih1, bih1, bhh1, ws);
  hipLaunchKernelGGL(k_lstm, dim3(NBLK), dim3(256), 0, stream,
                     x, c0, Whh1, Wih2, Whh2, bih2, bhh2, Wfc, bfc,
                     (float*)d_out, ws);
}